// Round 10
// baseline (15317.033 us; speedup 1.0000x reference)
//
#include <hip/hip_runtime.h>
#include <hip/hip_bf16.h>
#include <cstdint>
#include <cstddef>

// SimpleXLSTM persistent-kernel round 10.
// ONE change vs round 9: the 28 per-wave B-fragments are pinned into VGPRs
// with an opaque `asm volatile("" : "+v")` after the one-time load. Round 9's
// VGPR_Count=108 proved the compiler rematerialized the B loads inside the
// phase loop (needs 112 regs for B alone) -> ~917 MB/phase of L2 traffic
// (~27 us/phase, the flat residual since r6). The asm makes remat illegal.
// Everything else identical to verified round 9 (absmax 3.9e-3).

#define BATCH 128
#define SEQ   512
#define INP   512
#define HID   1024
#define NCOL  4096
#define NB    256
#define KS0   48
#define KS1   64
#define HS_   (BATCH * HID)

typedef __bf16 bf16x8 __attribute__((ext_vector_type(8)));
typedef float  f32x4  __attribute__((ext_vector_type(4)));
typedef unsigned int u32x4 __attribute__((ext_vector_type(4)));
typedef unsigned long long u64;
typedef u64 u64x2 __attribute__((ext_vector_type(2)));

__device__ __forceinline__ bf16x8 load_bf16x8(const __hip_bfloat16* p) {
    u32x4 u = *reinterpret_cast<const u32x4*>(p);
    return __builtin_bit_cast(bf16x8, u);
}
__device__ __forceinline__ bf16x8 aload_bf16x8(const __hip_bfloat16* p) {
    u64x2 q;
    q[0] = __hip_atomic_load((const u64*)p,       __ATOMIC_RELAXED, __HIP_MEMORY_SCOPE_AGENT);
    q[1] = __hip_atomic_load((const u64*)(p + 4), __ATOMIC_RELAXED, __HIP_MEMORY_SCOPE_AGENT);
    return __builtin_bit_cast(bf16x8, q);
}
__device__ __forceinline__ f32x4 mfma16(bf16x8 a, bf16x8 b, f32x4 c) {
    return __builtin_amdgcn_mfma_f32_16x16x32_bf16(a, b, c, 0, 0, 0);
}
__device__ __forceinline__ float sigmoidf_(float x) {
    return 1.0f / (1.0f + __expf(-x));
}
__device__ __forceinline__ float tanhf_(float x) {
    return 1.0f - 2.0f / (__expf(2.0f * x) + 1.0f);
}
// global -> LDS async copy, 16 B per lane; LDS dest = l + lane*16 (HW rule)
__device__ __forceinline__ void gload16(const void* g, void* l) {
    __builtin_amdgcn_global_load_lds(
        (const __attribute__((address_space(1))) uint32_t*)g,
        (__attribute__((address_space(3))) uint32_t*)l, 16, 0, 0);
}
#define VMWAIT asm volatile("s_waitcnt vmcnt(12)" ::: "memory")

// ---------------------------------------------------------------------------
// Prep kernels (verified rounds 2-9)
// ---------------------------------------------------------------------------
template<int Ks>
__global__ __launch_bounds__(1024)
void pack_frag_kernel(const float* __restrict__ W, __hip_bfloat16* __restrict__ F)
{
    __shared__ float tile[32][33];
    const int k0 = blockIdx.x * 32;
    const int c0 = blockIdx.y * 32;
    const int tx = threadIdx.x & 31, ty = threadIdx.x >> 5;
    tile[ty][tx] = W[(size_t)(k0 + ty) * NCOL + (c0 + tx)];
    __syncthreads();
    const int cL  = threadIdx.x >> 5;
    const int kgw = (threadIdx.x >> 3) & 3;
    const int j   = threadIdx.x & 7;
    const int c   = c0 + cL;
    const int r   = (c & 1023) * 4 + (c >> 10);
    const int nb2 = r >> 4, cl = r & 15;
    const int ks  = k0 >> 5;
    const size_t chunk = ((size_t)(nb2 * Ks + ks) * 4 + kgw) * 16 + cl;
    F[chunk * 8 + j] = __float2bfloat16(tile[kgw * 8 + j][cL]);
}

__global__ void bias_reorder_kernel(const float* __restrict__ b0,
                                    const float* __restrict__ b1,
                                    float* __restrict__ b0r,
                                    float* __restrict__ b1r)
{
    int i = blockIdx.x * blockDim.x + threadIdx.x;
    if (i >= 2 * NCOL) return;
    const float* src = (i < NCOL) ? b0 : b1;
    float*       dst = (i < NCOL) ? b0r : b1r;
    int c = i & (NCOL - 1);
    dst[(c & 1023) * 4 + (c >> 10)] = src[c];
}

// x -> bf16 in fragment order: xb[t*65536 + (((ks*2+mq)*4+kg)*64+r)*8 + j]
//   = x[b = mq*64+r][t][k = ks*32+kg*8+j]
__global__ __launch_bounds__(256)
void xconv_kernel(const float* __restrict__ x, __hip_bfloat16* __restrict__ xb)
{
    const int idx = blockIdx.x * 256 + threadIdx.x;     // 4,194,304 total
    const int r   = idx & 63;
    const int kg  = (idx >> 6) & 3;
    const int mq  = (idx >> 8) & 1;
    const int ks  = (idx >> 9) & 15;
    const int t   = idx >> 13;
    const float* src = x + ((size_t)(mq * 64 + r) * SEQ + t) * INP + ks * 32 + kg * 8;
    bf16x8 v;
    #pragma unroll
    for (int j = 0; j < 8; ++j) v[j] = (__bf16)src[j];
    *reinterpret_cast<u32x4*>(xb + (size_t)idx * 8) = __builtin_bit_cast(u32x4, v);
}

// ---------------------------------------------------------------------------
// Persistent kernel: 256 blocks x 512 threads (8 waves: kq 0..3 x mq 0..1).
// ---------------------------------------------------------------------------
__global__ __launch_bounds__(512, 2)
void lstm_persistent(const __hip_bfloat16* __restrict__ xb,
                     const __hip_bfloat16* __restrict__ F0,
                     const __hip_bfloat16* __restrict__ F1,
                     const float* __restrict__ b0r,
                     const float* __restrict__ b1r,
                     const float* __restrict__ Wout,
                     const float* __restrict__ bout,
                     __hip_bfloat16* __restrict__ h0r,
                     __hip_bfloat16* __restrict__ h1r,
                     float* __restrict__ out,
                     int* __restrict__ bar,
                     int rm, int fm)
{
    extern __shared__ char smem[];                 // 8 waves x 16 KB staging

    __shared__ float zacc[2][128][17];             // 17408 B
    __shared__ float cS[2][512];                   // 4096 B
    __shared__ float biasS[2][16];                 // 128 B
    __shared__ __hip_bfloat16 hstage[2][128][4];   // 2048 B

    const int tid  = threadIdx.x;
    const int lane = tid & 63;
    const int wv   = tid >> 6;          // 0..7
    const int kq   = wv & 3;
    const int mq   = wv >> 2;           // 0..1
    const int lm   = lane & 15;
    const int kg   = lane >> 4;
    const int nb   = blockIdx.x;
    const uint32_t sbase = (uint32_t)wv * 16384;

    // ---- one-time init: B-fragments into registers (phase-invariant) ----
    bf16x8 B0r_[12], B1r_[16];
    #pragma unroll
    for (int i = 0; i < 4; ++i)
        B0r_[i]     = load_bf16x8(F0 + ((((size_t)nb * KS0 + (4*kq + i)) * 4 + kg) * 16 + lm) * 8);
    #pragma unroll
    for (int i = 0; i < 8; ++i)
        B0r_[4 + i] = load_bf16x8(F0 + ((((size_t)nb * KS0 + (16 + 8*kq + i)) * 4 + kg) * 16 + lm) * 8);
    #pragma unroll
    for (int i = 0; i < 8; ++i)
        B1r_[i]     = load_bf16x8(F1 + ((((size_t)nb * KS1 + (8*kq + i)) * 4 + kg) * 16 + lm) * 8);
    #pragma unroll
    for (int i = 0; i < 8; ++i)
        B1r_[8 + i] = load_bf16x8(F1 + ((((size_t)nb * KS1 + (32 + 8*kq + i)) * 4 + kg) * 16 + lm) * 8);

    // PIN: opaque definition -> compiler cannot rematerialize the B loads
    // inside the phase loop (r9: VGPR=108 < 112 needed => it was re-loading
    // ~917 MB/phase from L2). Budget is 256 VGPRs (2 waves/EU); keep them.
    #pragma unroll
    for (int i = 0; i < 12; ++i) asm volatile("" : "+v"(B0r_[i]));
    #pragma unroll
    for (int i = 0; i < 16; ++i) asm volatile("" : "+v"(B1r_[i]));

    if (tid < 32) biasS[tid >> 4][tid & 15] = ((tid < 16) ? b0r : b1r)[nb * 16 + (tid & 15)];
    for (int i = tid; i < 1024; i += 512) cS[i >> 9][i & 511] = 0.f;
    for (int i = tid; i < 2 * 128 * 17; i += 512) ((float*)zacc)[i] = 0.f;
    __syncthreads();

    auto issueStep = [&](const __hip_bfloat16* src, int sl) {
        const char* g = (const char*)src + (size_t)lane * 16;
        char* l = smem + sbase + (uint32_t)sl * 4096;
        #pragma unroll
        for (int i2 = 0; i2 < 4; ++i2)
            gload16(g + i2 * 1024, l + i2 * 1024);
    };
    auto readA = [&](int sl, int f) -> bf16x8 {
        const char* lp = smem + sbase + (uint32_t)sl * 4096
                       + (uint32_t)kg * 1024 + (uint32_t)f * 256 + (uint32_t)lm * 16;
        u32x4 v = *(const u32x4*)lp;
        return __builtin_bit_cast(bf16x8, v);
    };

    // prologue: x(t=0) steps 0..3 -> slots 0..3
    #pragma unroll
    for (int s = 0; s < 4; ++s)
        issueStep(xb + ((size_t)((4*kq + s) * 2 + mq)) * 2048, s);

    for (int p = 0; p <= SEQ; ++p) {
        const __hip_bfloat16* h0p = h0r + (size_t)((p + rm)     & rm) * HS_;  // h0(p-1)
        const __hip_bfloat16* h1p = h1r + (size_t)((p + rm - 1) & rm) * HS_;  // h1(p-2)
        __hip_bfloat16*       h0w = h0r + (size_t)( p           & rm) * HS_;  // h0(p)
        __hip_bfloat16*       h1w = h1r + (size_t)((p + rm)     & rm) * HS_;  // h1(p-1)
        const int tn = (p + 1 < SEQ) ? (p + 1) : (SEQ - 1);

        f32x4 aL0[4], aL1[4];
        #pragma unroll
        for (int f = 0; f < 4; ++f) { aL0[f] = f32x4{0,0,0,0}; aL1[f] = f32x4{0,0,0,0}; }

        // ---- x section: consume steps 0..3, issue h0 steps 0..3 ----
        #pragma unroll
        for (int s = 0; s < 4; ++s) {
            VMWAIT;
            bf16x8 A[4];
            #pragma unroll
            for (int f = 0; f < 4; ++f) A[f] = readA(s, f);
            #pragma unroll
            for (int f = 0; f < 4; ++f) aL0[f] = mfma16(A[f], B0r_[s], aL0[f]);
            issueStep(h0p + ((size_t)((8*kq + s) * 2 + mq)) * 2048, s);  // step 4+s
        }
        // ---- h0 section: consume steps 4..11 (dual MFMA), issue h0 4..7 / h1 0..3 ----
        #pragma unroll
        for (int i = 0; i < 8; ++i) {
            VMWAIT;
            const int sl = (4 + i) & 3;
            bf16x8 A[4];
            #pragma unroll
            for (int f = 0; f < 4; ++f) A[f] = readA(sl, f);
            #pragma unroll
            for (int f = 0; f < 4; ++f) {
                aL0[f] = mfma16(A[f], B0r_[4 + i], aL0[f]);
                aL1[f] = mfma16(A[f], B1r_[i],     aL1[f]);
            }
            if (i < 4) issueStep(h0p + ((size_t)((8*kq + 4 + i)   * 2 + mq)) * 2048, (8 + i) & 3);
            else       issueStep(h1p + ((size_t)((8*kq + (i - 4)) * 2 + mq)) * 2048, (8 + i) & 3);
        }
        // ---- h1 section: consume steps 12..19, issue h1 4..7 / next-phase x ----
        #pragma unroll
        for (int i = 0; i < 8; ++i) {
            VMWAIT;
            const int sl = (12 + i) & 3;
            bf16x8 A[4];
            #pragma unroll
            for (int f = 0; f < 4; ++f) A[f] = readA(sl, f);
            #pragma unroll
            for (int f = 0; f < 4; ++f) aL1[f] = mfma16(A[f], B1r_[8 + i], aL1[f]);
            if (i < 4)
                issueStep(h1p + ((size_t)((8*kq + 4 + i) * 2 + mq)) * 2048, (16 + i) & 3);
            else if (p < SEQ)
                issueStep(xb + (size_t)tn * 65536
                             + ((size_t)((4*kq + (i - 4)) * 2 + mq)) * 2048, (16 + i) & 3);
        }

        // ---- z partial reduction (LDS atomics; 4 kq waves per cell) ----
        if (p < SEQ) {
            #pragma unroll
            for (int f = 0; f < 4; ++f)
                #pragma unroll
                for (int r = 0; r < 4; ++r)
                    atomicAdd(&zacc[0][mq*64 + f*16 + kg*4 + r][lm], aL0[f][r]);
        }
        if (p >= 1) {
            #pragma unroll
            for (int f = 0; f < 4; ++f)
                #pragma unroll
                for (int r = 0; r < 4; ++r)
                    atomicAdd(&zacc[1][mq*64 + f*16 + kg*4 + r][lm], aL1[f][r]);
        }
        __syncthreads();

        // ---- gates (1024 units over 512 threads) ----
        for (int it = tid; it < 1024; it += 512) {
            const int L   = it >> 9;
            const int idx = it & 511;
            const int bl  = idx >> 2;
            const int u   = idx & 3;
            const bool act = L ? (p >= 1) : (p < SEQ);
            if (act) {
                float* zb = &zacc[L][bl][4 * u];
                const float zf = zb[0] + biasS[L][4*u + 0];
                const float zi = zb[1] + biasS[L][4*u + 1];
                const float zo = zb[2] + biasS[L][4*u + 2];
                const float zg = zb[3] + biasS[L][4*u + 3];
                zb[0] = 0.f; zb[1] = 0.f; zb[2] = 0.f; zb[3] = 0.f;
                const float cold = cS[L][idx];
                const float cn = sigmoidf_(zf) * cold + sigmoidf_(zi) * tanhf_(zg);
                const float hn = sigmoidf_(zo) * tanhf_(cn);
                cS[L][idx] = cn;
                hstage[L][bl][u] = __float2bfloat16(hn);
            }
        }
        __syncthreads();

        // ---- 8B bypass stores of h into fragment-ordered ring ----
        if (tid < 256) {
            const int L  = tid >> 7;
            const int bl = tid & 127;
            const bool act = L ? (p >= 1) : (p < SEQ);
            if (act) {
                __hip_bfloat16* hw = L ? h1w : h0w;
                const int uks = nb >> 3, ukg = (nb >> 1) & 3, jb = (nb & 1) * 4;
                const int mqb = bl >> 6, rr = bl & 63;
                const size_t e = ((size_t)((uks*2 + mqb)*4 + ukg)*64 + rr)*8 + jb;
                const u64 v = *(const u64*)&hstage[L][bl][0];
                __hip_atomic_store((u64*)(hw + e), v,
                                   __ATOMIC_RELAXED, __HIP_MEMORY_SCOPE_AGENT);
            }
        }
        __syncthreads();   // drains vmcnt for every wave -> stores at L3

        // ---- low-contention tree barrier (verified r7-r9) ----
        if (tid == 0) {
            const int g = nb >> 5;
            int* arrv = bar + 32 * g;
            int* root = bar + 256;
            int* rel  = bar + 512 + 32 * g;
            const int e = p + 1;
            __hip_atomic_fetch_add(arrv, 1, __ATOMIC_RELAXED, __HIP_MEMORY_SCOPE_AGENT);
            if ((nb & 31) == 0) {
                while (__hip_atomic_load(arrv, __ATOMIC_RELAXED, __HIP_MEMORY_SCOPE_AGENT) < 32 * e)
                    __builtin_amdgcn_s_sleep(1);
                __hip_atomic_fetch_add(root, 1, __ATOMIC_RELAXED, __HIP_MEMORY_SCOPE_AGENT);
            }
            if (nb == 0) {
                while (__hip_atomic_load(root, __ATOMIC_RELAXED, __HIP_MEMORY_SCOPE_AGENT) < 8 * e)
                    __builtin_amdgcn_s_sleep(1);
                #pragma unroll
                for (int gg = 0; gg < 8; ++gg)
                    __hip_atomic_store(bar + 512 + 32 * gg, e,
                                       __ATOMIC_RELAXED, __HIP_MEMORY_SCOPE_AGENT);
            } else {
                while (__hip_atomic_load(rel, __ATOMIC_RELAXED, __HIP_MEMORY_SCOPE_AGENT) < e)
                    __builtin_amdgcn_s_sleep(2);
            }
            if ((p & fm) == fm)
                __builtin_amdgcn_fence(__ATOMIC_ACQUIRE, "agent");  // bound cache lifetime
            asm volatile("" ::: "memory");
        }
        __builtin_amdgcn_s_barrier();   // raw: no extra vmcnt drain
    }

    // ---- head: out[b] = sigmoid(h1(511) . Wout + bout) ----
    if (nb == 0 && tid < BATCH) {
        const __hip_bfloat16* hb = h1r + (size_t)((SEQ - 1) & rm) * HS_;
        const int mqb = tid >> 6, rr = tid & 63;
        float acc = 0.f;
        for (int uu = 0; uu < HID; uu += 8) {
            const int uks = uu >> 5, ukg = (uu >> 3) & 3;
            const size_t e = ((size_t)((uks*2 + mqb)*4 + ukg)*64 + rr)*8;
            bf16x8 v = aload_bf16x8(hb + e);
            #pragma unroll
            for (int j = 0; j < 8; ++j) acc += (float)v[j] * Wout[uu + j];
        }
        out[tid] = 1.f / (1.f + __expf(-(acc + bout[0])));
    }
}

// ---------------------------------------------------------------------------
extern "C" void kernel_launch(void* const* d_in, const int* in_sizes, int n_in,
                              void* d_out, int out_size, void* d_ws, size_t ws_size,
                              hipStream_t stream)
{
    const float* x    = (const float*)d_in[0];
    const float* W0   = (const float*)d_in[1];
    const float* b0   = (const float*)d_in[2];
    const float* W1   = (const float*)d_in[3];
    const float* b1   = (const float*)d_in[4];
    const float* Wout = (const float*)d_in[5];
    const float* bout = (const float*)d_in[6];
    float* out = (float*)d_out;

    char* ws = (char*)d_ws;
    const size_t OFF_F0  = 0;            // 12,582,912
    const size_t OFF_F1  = 12582912;     // +16,777,216 -> 29,360,128
    const size_t OFF_B0R = 29360128;
    const size_t OFF_B1R = 29376512;
    const size_t OFF_BAR = 29392896;     // 4096
    const size_t OFF_R0  = 29396992;
    const size_t SLOT    = 262144;       // 128*1024*2 B
    const size_t XBYTES  = (size_t)BATCH * SEQ * INP * 2;   // 67,108,864

    // ring-size tiers by available workspace (all correct; bigger = faster)
    int rm, fm;
    if      (ws_size >= OFF_R0 + 128 * SLOT + XBYTES) { rm = 63; fm = 31; }
    else if (ws_size >= OFF_R0 +  32 * SLOT + XBYTES) { rm = 15; fm = 7;  }
    else                                              { rm = 1;  fm = 0;  }
    const size_t OFF_R1 = OFF_R0 + (size_t)(rm + 1) * SLOT;
    const size_t OFF_XB = OFF_R1 + (size_t)(rm + 1) * SLOT;

    __hip_bfloat16* F0  = (__hip_bfloat16*)(ws + OFF_F0);
    __hip_bfloat16* F1  = (__hip_bfloat16*)(ws + OFF_F1);
    float* b0r = (float*)(ws + OFF_B0R);
    float* b1r = (float*)(ws + OFF_B1R);
    __hip_bfloat16* h0r = (__hip_bfloat16*)(ws + OFF_R0);
    __hip_bfloat16* h1r = (__hip_bfloat16*)(ws + OFF_R1);
    int* bar = (int*)(ws + OFF_BAR);
    __hip_bfloat16* xbp = (__hip_bfloat16*)(ws + OFF_XB);

    // per-call reset: barrier epochs + the t=-1 ring slots (slot rm)
    hipMemsetAsync(ws + OFF_BAR, 0, 4096, stream);
    hipMemsetAsync(ws + OFF_R0 + (size_t)rm * SLOT, 0, SLOT, stream);
    hipMemsetAsync(ws + OFF_R1 + (size_t)rm * SLOT, 0, SLOT, stream);

    pack_frag_kernel<KS0><<<dim3(48, 128), 1024, 0, stream>>>(W0, F0);
    pack_frag_kernel<KS1><<<dim3(64, 128), 1024, 0, stream>>>(W1, F1);
    bias_reorder_kernel<<<32, 256, 0, stream>>>(b0, b1, b0r, b1r);
    xconv_kernel<<<(BATCH * SEQ * INP) / (256 * 8), 256, 0, stream>>>(x, xbp);

    hipFuncSetAttribute((const void*)lstm_persistent,
                        hipFuncAttributeMaxDynamicSharedMemorySize, 131072);

    void* args[] = {(void*)&xbp, (void*)&F0, (void*)&F1, (void*)&b0r, (void*)&b1r,
                    (void*)&Wout, (void*)&bout, (void*)&h0r, (void*)&h1r,
                    (void*)&out, (void*)&bar, (void*)&rm, (void*)&fm};
    hipLaunchCooperativeKernel((void*)lstm_persistent, dim3(NB), dim3(512),
                               args, 131072, stream);
}

// Round 11
// 15227.055 us; speedup vs baseline: 1.0059x; 1.0059x over previous
//
#include <hip/hip_runtime.h>
#include <hip/hip_bf16.h>
#include <cstdint>
#include <cstddef>

// SimpleXLSTM persistent-kernel round 11.
// vs round 10: SPLIT grid barrier. Arrive posted right after the store-drain;
// the WAIT chain runs only after the next phase's x-section (which depends
// only on read-only xb) -> barrier detection latency + skew overlap with
// real MFMA work, and arrivals are ~a full phase body old when polled.
// x-consume loses its vmcnt waits (slots proven resident: the prior phase's
// store-drain syncthreads waits vmcnt(0) after the prefetch was issued).
// GEMM staging / rings / tiers identical to verified r9/r10 (absmax 3.9e-3).

#define BATCH 128
#define SEQ   512
#define INP   512
#define HID   1024
#define NCOL  4096
#define NB    256
#define KS0   48
#define KS1   64
#define HS_   (BATCH * HID)

typedef __bf16 bf16x8 __attribute__((ext_vector_type(8)));
typedef float  f32x4  __attribute__((ext_vector_type(4)));
typedef unsigned int u32x4 __attribute__((ext_vector_type(4)));
typedef unsigned long long u64;
typedef u64 u64x2 __attribute__((ext_vector_type(2)));

__device__ __forceinline__ bf16x8 load_bf16x8(const __hip_bfloat16* p) {
    u32x4 u = *reinterpret_cast<const u32x4*>(p);
    return __builtin_bit_cast(bf16x8, u);
}
__device__ __forceinline__ bf16x8 aload_bf16x8(const __hip_bfloat16* p) {
    u64x2 q;
    q[0] = __hip_atomic_load((const u64*)p,       __ATOMIC_RELAXED, __HIP_MEMORY_SCOPE_AGENT);
    q[1] = __hip_atomic_load((const u64*)(p + 4), __ATOMIC_RELAXED, __HIP_MEMORY_SCOPE_AGENT);
    return __builtin_bit_cast(bf16x8, q);
}
__device__ __forceinline__ f32x4 mfma16(bf16x8 a, bf16x8 b, f32x4 c) {
    return __builtin_amdgcn_mfma_f32_16x16x32_bf16(a, b, c, 0, 0, 0);
}
__device__ __forceinline__ float sigmoidf_(float x) {
    return 1.0f / (1.0f + __expf(-x));
}
__device__ __forceinline__ float tanhf_(float x) {
    return 1.0f - 2.0f / (__expf(2.0f * x) + 1.0f);
}
__device__ __forceinline__ void gload16(const void* g, void* l) {
    __builtin_amdgcn_global_load_lds(
        (const __attribute__((address_space(1))) uint32_t*)g,
        (__attribute__((address_space(3))) uint32_t*)l, 16, 0, 0);
}
#define VMWAIT asm volatile("s_waitcnt vmcnt(12)" ::: "memory")

// ---------------------------------------------------------------------------
// Prep kernels (verified rounds 2-10)
// ---------------------------------------------------------------------------
template<int Ks>
__global__ __launch_bounds__(1024)
void pack_frag_kernel(const float* __restrict__ W, __hip_bfloat16* __restrict__ F)
{
    __shared__ float tile[32][33];
    const int k0 = blockIdx.x * 32;
    const int c0 = blockIdx.y * 32;
    const int tx = threadIdx.x & 31, ty = threadIdx.x >> 5;
    tile[ty][tx] = W[(size_t)(k0 + ty) * NCOL + (c0 + tx)];
    __syncthreads();
    const int cL  = threadIdx.x >> 5;
    const int kgw = (threadIdx.x >> 3) & 3;
    const int j   = threadIdx.x & 7;
    const int c   = c0 + cL;
    const int r   = (c & 1023) * 4 + (c >> 10);
    const int nb2 = r >> 4, cl = r & 15;
    const int ks  = k0 >> 5;
    const size_t chunk = ((size_t)(nb2 * Ks + ks) * 4 + kgw) * 16 + cl;
    F[chunk * 8 + j] = __float2bfloat16(tile[kgw * 8 + j][cL]);
}

__global__ void bias_reorder_kernel(const float* __restrict__ b0,
                                    const float* __restrict__ b1,
                                    float* __restrict__ b0r,
                                    float* __restrict__ b1r)
{
    int i = blockIdx.x * blockDim.x + threadIdx.x;
    if (i >= 2 * NCOL) return;
    const float* src = (i < NCOL) ? b0 : b1;
    float*       dst = (i < NCOL) ? b0r : b1r;
    int c = i & (NCOL - 1);
    dst[(c & 1023) * 4 + (c >> 10)] = src[c];
}

__global__ __launch_bounds__(256)
void xconv_kernel(const float* __restrict__ x, __hip_bfloat16* __restrict__ xb)
{
    const int idx = blockIdx.x * 256 + threadIdx.x;
    const int r   = idx & 63;
    const int kg  = (idx >> 6) & 3;
    const int mq  = (idx >> 8) & 1;
    const int ks  = (idx >> 9) & 15;
    const int t   = idx >> 13;
    const float* src = x + ((size_t)(mq * 64 + r) * SEQ + t) * INP + ks * 32 + kg * 8;
    bf16x8 v;
    #pragma unroll
    for (int j = 0; j < 8; ++j) v[j] = (__bf16)src[j];
    *reinterpret_cast<u32x4*>(xb + (size_t)idx * 8) = __builtin_bit_cast(u32x4, v);
}

// ---------------------------------------------------------------------------
// Persistent kernel: 256 blocks x 512 threads (8 waves: kq 0..3 x mq 0..1).
// ---------------------------------------------------------------------------
__global__ __launch_bounds__(512, 2)
void lstm_persistent(const __hip_bfloat16* __restrict__ xb,
                     const __hip_bfloat16* __restrict__ F0,
                     const __hip_bfloat16* __restrict__ F1,
                     const float* __restrict__ b0r,
                     const float* __restrict__ b1r,
                     const float* __restrict__ Wout,
                     const float* __restrict__ bout,
                     __hip_bfloat16* __restrict__ h0r,
                     __hip_bfloat16* __restrict__ h1r,
                     float* __restrict__ out,
                     int* __restrict__ bar,
                     int rm, int fm)
{
    extern __shared__ char smem[];                 // 8 waves x 16 KB staging

    __shared__ float zacc[2][128][17];
    __shared__ float cS[2][512];
    __shared__ float biasS[2][16];
    __shared__ __hip_bfloat16 hstage[2][128][4];

    const int tid  = threadIdx.x;
    const int lane = tid & 63;
    const int wv   = tid >> 6;
    const int kq   = wv & 3;
    const int mq   = wv >> 2;
    const int lm   = lane & 15;
    const int kg   = lane >> 4;
    const int nb   = blockIdx.x;
    const uint32_t sbase = (uint32_t)wv * 16384;

    // ---- one-time: B-fragments into registers (AGPR-resident, r10 finding) ----
    bf16x8 B0r_[12], B1r_[16];
    #pragma unroll
    for (int i = 0; i < 4; ++i)
        B0r_[i]     = load_bf16x8(F0 + ((((size_t)nb * KS0 + (4*kq + i)) * 4 + kg) * 16 + lm) * 8);
    #pragma unroll
    for (int i = 0; i < 8; ++i)
        B0r_[4 + i] = load_bf16x8(F0 + ((((size_t)nb * KS0 + (16 + 8*kq + i)) * 4 + kg) * 16 + lm) * 8);
    #pragma unroll
    for (int i = 0; i < 8; ++i)
        B1r_[i]     = load_bf16x8(F1 + ((((size_t)nb * KS1 + (8*kq + i)) * 4 + kg) * 16 + lm) * 8);
    #pragma unroll
    for (int i = 0; i < 8; ++i)
        B1r_[8 + i] = load_bf16x8(F1 + ((((size_t)nb * KS1 + (32 + 8*kq + i)) * 4 + kg) * 16 + lm) * 8);
    #pragma unroll
    for (int i = 0; i < 12; ++i) asm volatile("" : "+v"(B0r_[i]));
    #pragma unroll
    for (int i = 0; i < 16; ++i) asm volatile("" : "+v"(B1r_[i]));

    if (tid < 32) biasS[tid >> 4][tid & 15] = ((tid < 16) ? b0r : b1r)[nb * 16 + (tid & 15)];
    for (int i = tid; i < 1024; i += 512) cS[i >> 9][i & 511] = 0.f;
    for (int i = tid; i < 2 * 128 * 17; i += 512) ((float*)zacc)[i] = 0.f;
    __syncthreads();

    auto issueStep = [&](const __hip_bfloat16* src, int sl) {
        const char* g = (const char*)src + (size_t)lane * 16;
        char* l = smem + sbase + (uint32_t)sl * 4096;
        #pragma unroll
        for (int i2 = 0; i2 < 4; ++i2)
            gload16(g + i2 * 1024, l + i2 * 1024);
    };
    auto readA = [&](int sl, int f) -> bf16x8 {
        const char* lp = smem + sbase + (uint32_t)sl * 4096
                       + (uint32_t)kg * 1024 + (uint32_t)f * 256 + (uint32_t)lm * 16;
        u32x4 v = *(const u32x4*)lp;
        return __builtin_bit_cast(bf16x8, v);
    };

    // prologue: x(t=0) steps 0..3 -> slots 0..3, then drain once so the
    // x-section never needs vmcnt waits (steady state: prefetch completes
    // before the prior phase's store-drain syncthreads).
    #pragma unroll
    for (int s = 0; s < 4; ++s)
        issueStep(xb + ((size_t)((4*kq + s) * 2 + mq)) * 2048, s);
    asm volatile("s_waitcnt vmcnt(0)" ::: "memory");

    for (int p = 0; p <= SEQ; ++p) {
        const __hip_bfloat16* h0p = h0r + (size_t)((p + rm)     & rm) * HS_;  // h0(p-1)
        const __hip_bfloat16* h1p = h1r + (size_t)((p + rm - 1) & rm) * HS_;  // h1(p-2)
        __hip_bfloat16*       h0w = h0r + (size_t)( p           & rm) * HS_;  // h0(p)
        __hip_bfloat16*       h1w = h1r + (size_t)((p + rm)     & rm) * HS_;  // h1(p-1)
        const int tn = (p + 1 < SEQ) ? (p + 1) : (SEQ - 1);

        f32x4 aL0[4], aL1[4];
        #pragma unroll
        for (int f = 0; f < 4; ++f) { aL0[f] = f32x4{0,0,0,0}; aL1[f] = f32x4{0,0,0,0}; }

        // ===== x-section (needs NO other block's data; slots resident) =====
        #pragma unroll
        for (int s = 0; s < 4; ++s) {
            bf16x8 A[4];
            #pragma unroll
            for (int f = 0; f < 4; ++f) A[f] = readA(s, f);
            #pragma unroll
            for (int f = 0; f < 4; ++f) aL0[f] = mfma16(A[f], B0r_[s], aL0[f]);
        }

        // ===== grid-barrier WAIT (arrivals were posted last phase end) =====
        // members: rel >= p; leaders: arrv >= 32p then root+=1;
        // block0: root >= 8(p+1) then release rel := p to all groups.
        if (tid == 0) {
            const int g = nb >> 5;
            int* arrv = bar + 32 * g;
            int* root = bar + 256;
            int* rel  = bar + 512 + 32 * g;
            if ((nb & 31) == 0) {
                while (__hip_atomic_load(arrv, __ATOMIC_RELAXED, __HIP_MEMORY_SCOPE_AGENT) < 32 * p)
                    __builtin_amdgcn_s_sleep(1);
                __hip_atomic_fetch_add(root, 1, __ATOMIC_RELAXED, __HIP_MEMORY_SCOPE_AGENT);
            }
            if (nb == 0) {
                while (__hip_atomic_load(root, __ATOMIC_RELAXED, __HIP_MEMORY_SCOPE_AGENT) < 8 * (p + 1))
                    __builtin_amdgcn_s_sleep(1);
                #pragma unroll
                for (int gg = 0; gg < 8; ++gg)
                    __hip_atomic_store(bar + 512 + 32 * gg, p,
                                       __ATOMIC_RELAXED, __HIP_MEMORY_SCOPE_AGENT);
            } else {
                while (__hip_atomic_load(rel, __ATOMIC_RELAXED, __HIP_MEMORY_SCOPE_AGENT) < p)
                    __builtin_amdgcn_s_sleep(2);
            }
            if ((p & fm) == fm)
                __builtin_amdgcn_fence(__ATOMIC_ACQUIRE, "agent");  // bound cache lifetime
            asm volatile("" ::: "memory");
        }
        __builtin_amdgcn_s_barrier();   // raw: keeps nothing extra waiting

        // ===== h0 section: burst-issue steps 4..7, then steady pipeline =====
        #pragma unroll
        for (int s = 0; s < 4; ++s)
            issueStep(h0p + ((size_t)((8*kq + s) * 2 + mq)) * 2048, s);
        #pragma unroll
        for (int i = 0; i < 8; ++i) {          // consume steps 4..11
            VMWAIT;
            const int sl = (4 + i) & 3;
            bf16x8 A[4];
            #pragma unroll
            for (int f = 0; f < 4; ++f) A[f] = readA(sl, f);
            #pragma unroll
            for (int f = 0; f < 4; ++f) {
                aL0[f] = mfma16(A[f], B0r_[4 + i], aL0[f]);
                aL1[f] = mfma16(A[f], B1r_[i],     aL1[f]);
            }
            if (i < 4) issueStep(h0p + ((size_t)((8*kq + 4 + i)   * 2 + mq)) * 2048, (8 + i) & 3);
            else       issueStep(h1p + ((size_t)((8*kq + (i - 4)) * 2 + mq)) * 2048, (8 + i) & 3);
        }
        // ===== h1 section: consume steps 12..19; issue h1 4..7 then next-x =====
        #pragma unroll
        for (int i = 0; i < 8; ++i) {
            VMWAIT;
            const int sl = (12 + i) & 3;
            bf16x8 A[4];
            #pragma unroll
            for (int f = 0; f < 4; ++f) A[f] = readA(sl, f);
            #pragma unroll
            for (int f = 0; f < 4; ++f) aL1[f] = mfma16(A[f], B1r_[8 + i], aL1[f]);
            if (i < 4)
                issueStep(h1p + ((size_t)((8*kq + 4 + i) * 2 + mq)) * 2048, (16 + i) & 3);
            else
                issueStep(xb + (size_t)tn * 65536
                             + ((size_t)((4*kq + (i - 4)) * 2 + mq)) * 2048, (16 + i) & 3);
        }

        // ---- z partial reduction (LDS atomics; 4 kq waves per cell) ----
        if (p < SEQ) {
            #pragma unroll
            for (int f = 0; f < 4; ++f)
                #pragma unroll
                for (int r = 0; r < 4; ++r)
                    atomicAdd(&zacc[0][mq*64 + f*16 + kg*4 + r][lm], aL0[f][r]);
        }
        if (p >= 1) {
            #pragma unroll
            for (int f = 0; f < 4; ++f)
                #pragma unroll
                for (int r = 0; r < 4; ++r)
                    atomicAdd(&zacc[1][mq*64 + f*16 + kg*4 + r][lm], aL1[f][r]);
        }
        __syncthreads();   // also completes the next-x prefetch (data lands)

        // ---- gates (1024 units over 512 threads) ----
        for (int it = tid; it < 1024; it += 512) {
            const int L   = it >> 9;
            const int idx = it & 511;
            const int bl  = idx >> 2;
            const int u   = idx & 3;
            const bool act = L ? (p >= 1) : (p < SEQ);
            if (act) {
                float* zb = &zacc[L][bl][4 * u];
                const float zf = zb[0] + biasS[L][4*u + 0];
                const float zi = zb[1] + biasS[L][4*u + 1];
                const float zo = zb[2] + biasS[L][4*u + 2];
                const float zg = zb[3] + biasS[L][4*u + 3];
                zb[0] = 0.f; zb[1] = 0.f; zb[2] = 0.f; zb[3] = 0.f;
                const float cold = cS[L][idx];
                const float cn = sigmoidf_(zf) * cold + sigmoidf_(zi) * tanhf_(zg);
                const float hn = sigmoidf_(zo) * tanhf_(cn);
                cS[L][idx] = cn;
                hstage[L][bl][u] = __float2bfloat16(hn);
            }
        }
        __syncthreads();

        // ---- 8B bypass stores of h into fragment-ordered ring ----
        if (tid < 256) {
            const int L  = tid >> 7;
            const int bl = tid & 127;
            const bool act = L ? (p >= 1) : (p < SEQ);
            if (act) {
                __hip_bfloat16* hw = L ? h1w : h0w;
                const int uks = nb >> 3, ukg = (nb >> 1) & 3, jb = (nb & 1) * 4;
                const int mqb = bl >> 6, rr = bl & 63;
                const size_t e = ((size_t)((uks*2 + mqb)*4 + ukg)*64 + rr)*8 + jb;
                const u64 v = *(const u64*)&hstage[L][bl][0];
                __hip_atomic_store((u64*)(hw + e), v,
                                   __ATOMIC_RELAXED, __HIP_MEMORY_SCOPE_AGENT);
            }
        }
        __syncthreads();   // drains every wave's vmcnt -> stores at L3

        // ===== ARRIVE (fire-and-forget; waited on in NEXT phase's WAIT) =====
        if (tid == 0)
            __hip_atomic_fetch_add(bar + 32 * (nb >> 5), 1,
                                   __ATOMIC_RELAXED, __HIP_MEMORY_SCOPE_AGENT);
    }

    // ---- head: wait for all blocks' final stores, then out[b] ----
    if (nb == 0) {
        if (tid == 0) {
            #pragma unroll
            for (int gg = 0; gg < 8; ++gg)
                while (__hip_atomic_load(bar + 32 * gg, __ATOMIC_RELAXED,
                                         __HIP_MEMORY_SCOPE_AGENT) < 32 * (SEQ + 1))
                    __builtin_amdgcn_s_sleep(2);
        }
        __syncthreads();
        if (tid < BATCH) {
            const __hip_bfloat16* hb = h1r + (size_t)((SEQ - 1) & rm) * HS_;
            const int mqb = tid >> 6, rr = tid & 63;
            float acc = 0.f;
            for (int uu = 0; uu < HID; uu += 8) {
                const int uks = uu >> 5, ukg = (uu >> 3) & 3;
                const size_t e = ((size_t)((uks*2 + mqb)*4 + ukg)*64 + rr)*8;
                bf16x8 v = aload_bf16x8(hb + e);
                #pragma unroll
                for (int j = 0; j < 8; ++j) acc += (float)v[j] * Wout[uu + j];
            }
            out[tid] = 1.f / (1.f + __expf(-(acc + bout[0])));
        }
    }
}

// ---------------------------------------------------------------------------
extern "C" void kernel_launch(void* const* d_in, const int* in_sizes, int n_in,
                              void* d_out, int out_size, void* d_ws, size_t ws_size,
                              hipStream_t stream)
{
    const float* x    = (const float*)d_in[0];
    const float* W0   = (const float*)d_in[1];
    const float* b0   = (const float*)d_in[2];
    const float* W1   = (const float*)d_in[3];
    const float* b1   = (const float*)d_in[4];
    const float* Wout = (const float*)d_in[5];
    const float* bout = (const float*)d_in[6];
    float* out = (float*)d_out;

    char* ws = (char*)d_ws;
    const size_t OFF_F0  = 0;            // 12,582,912
    const size_t OFF_F1  = 12582912;     // +16,777,216 -> 29,360,128
    const size_t OFF_B0R = 29360128;
    const size_t OFF_B1R = 29376512;
    const size_t OFF_BAR = 29392896;     // 4096
    const size_t OFF_R0  = 29396992;
    const size_t SLOT    = 262144;       // 128*1024*2 B
    const size_t XBYTES  = (size_t)BATCH * SEQ * INP * 2;   // 67,108,864

    int rm, fm;
    if      (ws_size >= OFF_R0 + 128 * SLOT + XBYTES) { rm = 63; fm = 31; }
    else if (ws_size >= OFF_R0 +  32 * SLOT + XBYTES) { rm = 15; fm = 7;  }
    else                                              { rm = 1;  fm = 0;  }
    const size_t OFF_R1 = OFF_R0 + (size_t)(rm + 1) * SLOT;
    const size_t OFF_XB = OFF_R1 + (size_t)(rm + 1) * SLOT;

    __hip_bfloat16* F0  = (__hip_bfloat16*)(ws + OFF_F0);
    __hip_bfloat16* F1  = (__hip_bfloat16*)(ws + OFF_F1);
    float* b0r = (float*)(ws + OFF_B0R);
    float* b1r = (float*)(ws + OFF_B1R);
    __hip_bfloat16* h0r = (__hip_bfloat16*)(ws + OFF_R0);
    __hip_bfloat16* h1r = (__hip_bfloat16*)(ws + OFF_R1);
    int* bar = (int*)(ws + OFF_BAR);
    __hip_bfloat16* xbp = (__hip_bfloat16*)(ws + OFF_XB);

    // per-call reset: barrier epochs + the t=-1 ring slots (slot rm)
    hipMemsetAsync(ws + OFF_BAR, 0, 4096, stream);
    hipMemsetAsync(ws + OFF_R0 + (size_t)rm * SLOT, 0, SLOT, stream);
    hipMemsetAsync(ws + OFF_R1 + (size_t)rm * SLOT, 0, SLOT, stream);

    pack_frag_kernel<KS0><<<dim3(48, 128), 1024, 0, stream>>>(W0, F0);
    pack_frag_kernel<KS1><<<dim3(64, 128), 1024, 0, stream>>>(W1, F1);
    bias_reorder_kernel<<<32, 256, 0, stream>>>(b0, b1, b0r, b1r);
    xconv_kernel<<<(BATCH * SEQ * INP) / (256 * 8), 256, 0, stream>>>(x, xbp);

    hipFuncSetAttribute((const void*)lstm_persistent,
                        hipFuncAttributeMaxDynamicSharedMemorySize, 131072);

    void* args[] = {(void*)&xbp, (void*)&F0, (void*)&F1, (void*)&b0r, (void*)&b1r,
                    (void*)&Wout, (void*)&bout, (void*)&h0r, (void*)&h1r,
                    (void*)&out, (void*)&bar, (void*)&rm, (void*)&fm};
    hipLaunchCooperativeKernel((void*)lstm_persistent, dim3(NB), dim3(512),
                               args, 131072, stream);
}

// Round 12
// 15114.070 us; speedup vs baseline: 1.0134x; 1.0075x over previous
//
#include <hip/hip_runtime.h>
#include <hip/hip_bf16.h>
#include <cstdint>
#include <cstddef>

// SimpleXLSTM persistent-kernel round 12.
// Key change vs r9-r11: M x U split. 256 blocks = 2 m-groups x 128 unit-blocks
// (8 units = 32 gate-cols). Each block reads h/x ONLY for its 64 batch rows:
// 320 KB/phase/CU instead of 640 KB. Rationale: every config r2..r11 converges
// to ~20-23 GB/s/CU effective streaming read BW (per-CU unique-line service
// ceiling, = the guide's ~10 B/cyc/CU constant); only reducing per-CU bytes
// moves the floor. Staging (gload_lds + vmcnt(12)), rings, split tree barrier
// all verbatim from verified r9-r11 (absmax 3.9e-3).

#define BATCH 128
#define SEQ   512
#define INP   512
#define HID   1024
#define NCOL  4096
#define NB    256
#define KS0   48
#define KS1   64
#define HSLOT 131072   // elems per h generation: 2 m x 128 ub x 64 r x 8 j

typedef __bf16 bf16x8 __attribute__((ext_vector_type(8)));
typedef float  f32x4  __attribute__((ext_vector_type(4)));
typedef unsigned int u32x4 __attribute__((ext_vector_type(4)));
typedef unsigned long long u64;
typedef u64 u64x2 __attribute__((ext_vector_type(2)));

__device__ __forceinline__ bf16x8 load_bf16x8(const __hip_bfloat16* p) {
    u32x4 u = *reinterpret_cast<const u32x4*>(p);
    return __builtin_bit_cast(bf16x8, u);
}
__device__ __forceinline__ bf16x8 aload_bf16x8(const __hip_bfloat16* p) {
    u64x2 q;
    q[0] = __hip_atomic_load((const u64*)p,       __ATOMIC_RELAXED, __HIP_MEMORY_SCOPE_AGENT);
    q[1] = __hip_atomic_load((const u64*)(p + 4), __ATOMIC_RELAXED, __HIP_MEMORY_SCOPE_AGENT);
    return __builtin_bit_cast(bf16x8, q);
}
__device__ __forceinline__ f32x4 mfma16(bf16x8 a, bf16x8 b, f32x4 c) {
    return __builtin_amdgcn_mfma_f32_16x16x32_bf16(a, b, c, 0, 0, 0);
}
__device__ __forceinline__ float sigmoidf_(float x) {
    return 1.0f / (1.0f + __expf(-x));
}
__device__ __forceinline__ float tanhf_(float x) {
    return 1.0f - 2.0f / (__expf(2.0f * x) + 1.0f);
}
__device__ __forceinline__ void gload16(const void* g, void* l) {
    __builtin_amdgcn_global_load_lds(
        (const __attribute__((address_space(1))) uint32_t*)g,
        (__attribute__((address_space(3))) uint32_t*)l, 16, 0, 0);
}
#define VMWAIT asm volatile("s_waitcnt vmcnt(12)" ::: "memory")

// ---------------------------------------------------------------------------
// Prep kernels.
// Weight pack: W [K][4096] fp32 -> F bf16 frag order:
//   F[(((ub*2+cq)*Ks + ks)*4 + kg)*128 + lm*8 + j] = W[ks*32+kg*8+j][c]
//   where c = gate*1024 + ub*8 + ulocal, cl = ulocal*4+gate, cq=cl>>4, lm=cl&15.
// ---------------------------------------------------------------------------
template<int Ks>
__global__ __launch_bounds__(1024)
void pack_frag_kernel(const float* __restrict__ W, __hip_bfloat16* __restrict__ F)
{
    __shared__ float tile[32][33];
    const int k0 = blockIdx.x * 32;
    const int c0 = blockIdx.y * 32;
    const int tx = threadIdx.x & 31, ty = threadIdx.x >> 5;
    tile[ty][tx] = W[(size_t)(k0 + ty) * NCOL + (c0 + tx)];
    __syncthreads();
    const int cL    = threadIdx.x >> 5;   // 0..31 col within tile
    const int k_off = threadIdx.x & 31;   // 0..31 k within tile
    const int c    = c0 + cL;
    const int gate = c >> 10, ug = c & 1023;
    const int ub   = ug >> 3, ul = ug & 7;
    const int cl   = ul * 4 + gate;
    const int cq   = cl >> 4, lm = cl & 15;
    const int ks   = k0 >> 5;
    const int kg   = (k_off >> 3) & 3;
    const int j    = k_off & 7;
    F[((((size_t)(ub * 2 + cq) * Ks + ks) * 4 + kg) * 128) + lm * 8 + j] =
        __float2bfloat16(tile[k_off][cL]);
}

__global__ void bias_reorder_kernel(const float* __restrict__ b0,
                                    const float* __restrict__ b1,
                                    float* __restrict__ b0r,
                                    float* __restrict__ b1r)
{
    int i = blockIdx.x * blockDim.x + threadIdx.x;
    if (i >= 2 * NCOL) return;
    const float* src = (i < NCOL) ? b0 : b1;
    float*       dst = (i < NCOL) ? b0r : b1r;
    int c = i & (NCOL - 1);
    int gate = c >> 10, ug = c & 1023;
    dst[(ug >> 3) * 32 + (ug & 7) * 4 + gate] = src[c];
}

// x -> bf16 frag order: xb[t*65536 + m*32768 + ks*2048 + kg*512 + r*8 + j]
//   = x[b=m*64+r][t][k=ks*32+kg*8+j]
__global__ __launch_bounds__(256)
void xconv_kernel(const float* __restrict__ x, __hip_bfloat16* __restrict__ xb)
{
    const int g  = blockIdx.x * 256 + threadIdx.x;   // granule id, 4,194,304
    const int r  = g & 63;
    const int kg = (g >> 6) & 3;
    const int ks = (g >> 8) & 15;
    const int m  = (g >> 12) & 1;
    const int t  = g >> 13;
    const float* src = x + ((size_t)(m * 64 + r) * SEQ + t) * INP + ks * 32 + kg * 8;
    bf16x8 v;
    #pragma unroll
    for (int j = 0; j < 8; ++j) v[j] = (__bf16)src[j];
    *reinterpret_cast<u32x4*>(xb + (size_t)g * 8) = __builtin_bit_cast(u32x4, v);
}

// ---------------------------------------------------------------------------
// Persistent kernel: 256 blocks (= 2 m x 128 ub) x 512 threads
// (8 waves: kq 0..3 x cq 0..1). Block computes z[64 rows][32 cols].
// ---------------------------------------------------------------------------
__global__ __launch_bounds__(512, 2)
void lstm_persistent(const __hip_bfloat16* __restrict__ xb,
                     const __hip_bfloat16* __restrict__ F0,
                     const __hip_bfloat16* __restrict__ F1,
                     const float* __restrict__ b0r,
                     const float* __restrict__ b1r,
                     const float* __restrict__ Wout,
                     const float* __restrict__ bout,
                     __hip_bfloat16* __restrict__ h0r,
                     __hip_bfloat16* __restrict__ h1r,
                     float* __restrict__ out,
                     int* __restrict__ bar,
                     int rm, int fm)
{
    extern __shared__ char smem[];                 // 8 waves x 16 KB staging

    __shared__ float zacc[2][64][33];              // 16896 B
    __shared__ float cS[2][512];                   // c state: [L][bl*8+u]
    __shared__ float biasS[2][32];
    __shared__ __hip_bfloat16 hstage[2][64][8];    // 2048 B

    const int tid  = threadIdx.x;
    const int lane = tid & 63;
    const int wv   = tid >> 6;          // 0..7
    const int kq   = wv & 3;
    const int cq   = wv >> 2;           // 0..1 column half
    const int lm   = lane & 15;
    const int kg   = lane >> 4;
    const int nb   = blockIdx.x;
    const int m_blk = nb & 1;           // m-group (XCD round-robin keeps both on all XCDs)
    const int ub    = nb >> 1;          // unit-block 0..127
    const uint32_t sbase = (uint32_t)wv * 16384;

    // ---- one-time: B-fragments into registers (phase-invariant) ----
    const __hip_bfloat16* f0b = F0 + (size_t)(ub * 2 + cq) * (KS0 * 512);
    const __hip_bfloat16* f1b = F1 + (size_t)(ub * 2 + cq) * (KS1 * 512);
    bf16x8 B0r_[12], B1r_[16];
    #pragma unroll
    for (int i = 0; i < 4; ++i)          // x part: W0-ks = kq + 4i
        B0r_[i]     = load_bf16x8(f0b + ((size_t)(kq + 4*i) * 4 + kg) * 128 + lm * 8);
    #pragma unroll
    for (int i = 0; i < 8; ++i)          // h0 part: W0-ks = 16 + 8kq + i
        B0r_[4 + i] = load_bf16x8(f0b + ((size_t)(16 + 8*kq + i) * 4 + kg) * 128 + lm * 8);
    #pragma unroll
    for (int i = 0; i < 8; ++i)          // h0 part of W1: ks = 8kq + i
        B1r_[i]     = load_bf16x8(f1b + ((size_t)(8*kq + i) * 4 + kg) * 128 + lm * 8);
    #pragma unroll
    for (int i = 0; i < 8; ++i)          // h1 part of W1: ks = 32 + 8kq + i
        B1r_[8 + i] = load_bf16x8(f1b + ((size_t)(32 + 8*kq + i) * 4 + kg) * 128 + lm * 8);

    if (tid < 64) biasS[tid >> 5][tid & 31] = ((tid < 32) ? b0r : b1r)[ub * 32 + (tid & 31)];
    for (int i = tid; i < 1024; i += 512) cS[i >> 9][i & 511] = 0.f;
    for (int i = tid; i < 2 * 64 * 33; i += 512) ((float*)zacc)[i] = 0.f;
    __syncthreads();

    auto issueStep = [&](const __hip_bfloat16* src, int sl) {
        const char* g = (const char*)src + (size_t)lane * 16;
        char* l = smem + sbase + (uint32_t)sl * 4096;
        #pragma unroll
        for (int i2 = 0; i2 < 4; ++i2)
            gload16(g + i2 * 1024, l + i2 * 1024);
    };
    auto readA = [&](int sl, int f) -> bf16x8 {
        const char* lp = smem + sbase + (uint32_t)sl * 4096
                       + (uint32_t)kg * 1024 + (uint32_t)f * 256 + (uint32_t)lm * 16;
        u32x4 v = *(const u32x4*)lp;
        return __builtin_bit_cast(bf16x8, v);
    };

    // prologue: x(t=0) steps (kq + 4s) -> slots 0..3, then one-time drain
    #pragma unroll
    for (int s = 0; s < 4; ++s)
        issueStep(xb + (size_t)m_blk * 32768 + (size_t)(kq + 4*s) * 2048, s);
    asm volatile("s_waitcnt vmcnt(0)" ::: "memory");

    for (int p = 0; p <= SEQ; ++p) {
        // h layout: slot*HSLOT + m*65536 + ub*512 + r*8 + j  (unit = ub*8+j)
        const __hip_bfloat16* h0p = h0r + (size_t)((p + rm)     & rm) * HSLOT + (size_t)m_blk * 65536;
        const __hip_bfloat16* h1p = h1r + (size_t)((p + rm - 1) & rm) * HSLOT + (size_t)m_blk * 65536;
        __hip_bfloat16*       h0w = h0r + (size_t)( p           & rm) * HSLOT;
        __hip_bfloat16*       h1w = h1r + (size_t)((p + rm)     & rm) * HSLOT;
        const int tn = (p + 1 < SEQ) ? (p + 1) : (SEQ - 1);

        f32x4 aL0[4], aL1[4];
        #pragma unroll
        for (int f = 0; f < 4; ++f) { aL0[f] = f32x4{0,0,0,0}; aL1[f] = f32x4{0,0,0,0}; }

        // ===== x-section (depends only on read-only xb; slots resident) =====
        #pragma unroll
        for (int s = 0; s < 4; ++s) {
            bf16x8 A[4];
            #pragma unroll
            for (int f = 0; f < 4; ++f) A[f] = readA(s, f);
            #pragma unroll
            for (int f = 0; f < 4; ++f) aL0[f] = mfma16(A[f], B0r_[s], aL0[f]);
        }

        // ===== grid-barrier WAIT (arrivals posted at end of prior phase) =====
        if (tid == 0) {
            const int g = nb >> 5;
            int* arrv = bar + 32 * g;
            int* root = bar + 256;
            int* rel  = bar + 512 + 32 * g;
            if ((nb & 31) == 0) {
                while (__hip_atomic_load(arrv, __ATOMIC_RELAXED, __HIP_MEMORY_SCOPE_AGENT) < 32 * p)
                    __builtin_amdgcn_s_sleep(1);
                __hip_atomic_fetch_add(root, 1, __ATOMIC_RELAXED, __HIP_MEMORY_SCOPE_AGENT);
            }
            if (nb == 0) {
                while (__hip_atomic_load(root, __ATOMIC_RELAXED, __HIP_MEMORY_SCOPE_AGENT) < 8 * (p + 1))
                    __builtin_amdgcn_s_sleep(1);
                #pragma unroll
                for (int gg = 0; gg < 8; ++gg)
                    __hip_atomic_store(bar + 512 + 32 * gg, p,
                                       __ATOMIC_RELAXED, __HIP_MEMORY_SCOPE_AGENT);
            } else {
                while (__hip_atomic_load(rel, __ATOMIC_RELAXED, __HIP_MEMORY_SCOPE_AGENT) < p)
                    __builtin_amdgcn_s_sleep(2);
            }
            if ((p & fm) == fm)
                __builtin_amdgcn_fence(__ATOMIC_ACQUIRE, "agent");  // bound cache lifetime
            asm volatile("" ::: "memory");
        }
        __builtin_amdgcn_s_barrier();   // raw: no vmcnt drain

        // ===== h0 section: burst-issue 4 steps, pipeline 8 (dual MFMA) =====
        #pragma unroll
        for (int s = 0; s < 4; ++s)
            issueStep(h0p + (size_t)(8*kq + s) * 2048, s);
        #pragma unroll
        for (int i = 0; i < 8; ++i) {
            VMWAIT;
            const int sl = i & 3;
            bf16x8 A[4];
            #pragma unroll
            for (int f = 0; f < 4; ++f) A[f] = readA(sl, f);
            #pragma unroll
            for (int f = 0; f < 4; ++f) {
                aL0[f] = mfma16(A[f], B0r_[4 + i], aL0[f]);
                aL1[f] = mfma16(A[f], B1r_[i],     aL1[f]);
            }
            if (i < 4) issueStep(h0p + (size_t)(8*kq + 4 + i) * 2048, i & 3);
            else       issueStep(h1p + (size_t)(8*kq + (i-4)) * 2048, i & 3);
        }
        // ===== h1 section: pipeline 8; tail issues next-phase x =====
        #pragma unroll
        for (int i = 0; i < 8; ++i) {
            VMWAIT;
            const int sl = i & 3;
            bf16x8 A[4];
            #pragma unroll
            for (int f = 0; f < 4; ++f) A[f] = readA(sl, f);
            #pragma unroll
            for (int f = 0; f < 4; ++f) aL1[f] = mfma16(A[f], B1r_[8 + i], aL1[f]);
            if (i < 4)
                issueStep(h1p + (size_t)(8*kq + 4 + i) * 2048, i & 3);
            else
                issueStep(xb + (size_t)tn * 65536 + (size_t)m_blk * 32768
                             + (size_t)(kq + 4*(i-4)) * 2048, i & 3);
        }

        // ---- z partial reduction (LDS atomics over 4 kq waves) ----
        if (p < SEQ) {
            #pragma unroll
            for (int f = 0; f < 4; ++f)
                #pragma unroll
                for (int r = 0; r < 4; ++r)
                    atomicAdd(&zacc[0][f*16 + kg*4 + r][cq*16 + lm], aL0[f][r]);
        }
        if (p >= 1) {
            #pragma unroll
            for (int f = 0; f < 4; ++f)
                #pragma unroll
                for (int r = 0; r < 4; ++r)
                    atomicAdd(&zacc[1][f*16 + kg*4 + r][cq*16 + lm], aL1[f][r]);
        }
        __syncthreads();   // also completes the next-x prefetch

        // ---- gates: 2 L x 64 rows x 8 units = 1024 cells / 512 threads ----
        for (int it = tid; it < 1024; it += 512) {
            const int L   = it >> 9;
            const int idx = it & 511;
            const int bl  = idx >> 3;      // row 0..63
            const int u   = idx & 7;       // unit 0..7
            const bool act = L ? (p >= 1) : (p < SEQ);
            if (act) {
                float* zb = &zacc[L][bl][4 * u];
                const float zf = zb[0] + biasS[L][4*u + 0];
                const float zi = zb[1] + biasS[L][4*u + 1];
                const float zo = zb[2] + biasS[L][4*u + 2];
                const float zg = zb[3] + biasS[L][4*u + 3];
                zb[0] = 0.f; zb[1] = 0.f; zb[2] = 0.f; zb[3] = 0.f;
                const float cold = cS[L][idx];
                const float cn = sigmoidf_(zf) * cold + sigmoidf_(zi) * tanhf_(zg);
                const float hn = sigmoidf_(zo) * tanhf_(cn);
                cS[L][idx] = cn;
                hstage[L][bl][u] = __float2bfloat16(hn);
            }
        }
        __syncthreads();

        // ---- h stores: 128 lanes x 16B (full granules, 2x8B bypass) ----
        if (tid < 128) {
            const int L  = tid >> 6;
            const int rr = tid & 63;
            const bool act = L ? (p >= 1) : (p < SEQ);
            if (act) {
                __hip_bfloat16* hw = (L ? h1w : h0w)
                                   + (size_t)m_blk * 65536 + (size_t)ub * 512 + (size_t)rr * 8;
                const u64* v = (const u64*)&hstage[L][rr][0];
                __hip_atomic_store((u64*)hw,       v[0], __ATOMIC_RELAXED, __HIP_MEMORY_SCOPE_AGENT);
                __hip_atomic_store((u64*)(hw + 4), v[1], __ATOMIC_RELAXED, __HIP_MEMORY_SCOPE_AGENT);
            }
        }
        __syncthreads();   // drains every wave's vmcnt -> stores at L3

        // ===== ARRIVE (waited on in NEXT phase) =====
        if (tid == 0)
            __hip_atomic_fetch_add(bar + 32 * (nb >> 5), 1,
                                   __ATOMIC_RELAXED, __HIP_MEMORY_SCOPE_AGENT);
    }

    // ---- head: wait all final stores, then out[b] = sigmoid(h1.Wout+b) ----
    if (nb == 0) {
        if (tid == 0) {
            #pragma unroll
            for (int gg = 0; gg < 8; ++gg)
                while (__hip_atomic_load(bar + 32 * gg, __ATOMIC_RELAXED,
                                         __HIP_MEMORY_SCOPE_AGENT) < 32 * (SEQ + 1))
                    __builtin_amdgcn_s_sleep(2);
        }
        __syncthreads();
        if (tid < BATCH) {
            const __hip_bfloat16* hb = h1r + (size_t)((SEQ - 1) & rm) * HSLOT
                                     + (size_t)(tid >> 6) * 65536 + (size_t)(tid & 63) * 8;
            float acc = 0.f;
            for (int ub2 = 0; ub2 < 128; ++ub2) {
                bf16x8 v = aload_bf16x8(hb + (size_t)ub2 * 512);
                #pragma unroll
                for (int j = 0; j < 8; ++j) acc += (float)v[j] * Wout[ub2 * 8 + j];
            }
            out[tid] = 1.f / (1.f + __expf(-(acc + bout[0])));
        }
    }
}

// ---------------------------------------------------------------------------
extern "C" void kernel_launch(void* const* d_in, const int* in_sizes, int n_in,
                              void* d_out, int out_size, void* d_ws, size_t ws_size,
                              hipStream_t stream)
{
    const float* x    = (const float*)d_in[0];
    const float* W0   = (const float*)d_in[1];
    const float* b0   = (const float*)d_in[2];
    const float* W1   = (const float*)d_in[3];
    const float* b1   = (const float*)d_in[4];
    const float* Wout = (const float*)d_in[5];
    const float* bout = (const float*)d_in[6];
    float* out = (float*)d_out;

    char* ws = (char*)d_ws;
    const size_t OFF_F0  = 0;            // 12,582,912
    const size_t OFF_F1  = 12582912;     // +16,777,216 -> 29,360,128
    const size_t OFF_B0R = 29360128;
    const size_t OFF_B1R = 29376512;
    const size_t OFF_BAR = 29392896;     // 4096
    const size_t OFF_R0  = 29396992;
    const size_t SLOT    = 262144;       // HSLOT elems x 2B
    const size_t XBYTES  = (size_t)BATCH * SEQ * INP * 2;   // 67,108,864

    int rm, fm;
    if      (ws_size >= OFF_R0 + 128 * SLOT + XBYTES) { rm = 63; fm = 31; }
    else if (ws_size >= OFF_R0 +  32 * SLOT + XBYTES) { rm = 15; fm = 7;  }
    else                                              { rm = 1;  fm = 0;  }
    const size_t OFF_R1 = OFF_R0 + (size_t)(rm + 1) * SLOT;
    const size_t OFF_XB = OFF_R1 + (size_t)(rm + 1) * SLOT;

    __hip_bfloat16* F0  = (__hip_bfloat16*)(ws + OFF_F0);
    __hip_bfloat16* F1  = (__hip_bfloat16*)(ws + OFF_F1);
    float* b0r = (float*)(ws + OFF_B0R);
    float* b1r = (float*)(ws + OFF_B1R);
    __hip_bfloat16* h0r = (__hip_bfloat16*)(ws + OFF_R0);
    __hip_bfloat16* h1r = (__hip_bfloat16*)(ws + OFF_R1);
    int* bar = (int*)(ws + OFF_BAR);
    __hip_bfloat16* xbp = (__hip_bfloat16*)(ws + OFF_XB);

    // per-call reset: barrier epochs + the t=-1 ring slots (slot rm)
    hipMemsetAsync(ws + OFF_BAR, 0, 4096, stream);
    hipMemsetAsync(ws + OFF_R0 + (size_t)rm * SLOT, 0, SLOT, stream);
    hipMemsetAsync(ws + OFF_R1 + (size_t)rm * SLOT, 0, SLOT, stream);

    pack_frag_kernel<KS0><<<dim3(48, 128), 1024, 0, stream>>>(W0, F0);
    pack_frag_kernel<KS1><<<dim3(64, 128), 1024, 0, stream>>>(W1, F1);
    bias_reorder_kernel<<<32, 256, 0, stream>>>(b0, b1, b0r, b1r);
    xconv_kernel<<<(BATCH * SEQ * INP) / (256 * 8), 256, 0, stream>>>(x, xbp);

    hipFuncSetAttribute((const void*)lstm_persistent,
                        hipFuncAttributeMaxDynamicSharedMemorySize, 131072);

    void* args[] = {(void*)&xbp, (void*)&F0, (void*)&F1, (void*)&b0r, (void*)&b1r,
                    (void*)&Wout, (void*)&bout, (void*)&h0r, (void*)&h1r,
                    (void*)&out, (void*)&bar, (void*)&rm, (void*)&fm};
    hipLaunchCooperativeKernel((void*)lstm_persistent, dim3(NB), dim3(512),
                               args, 131072, stream);
}